// Round 2
// baseline (201.645 us; speedup 1.0000x reference)
//
#include <hip/hip_runtime.h>

// RadialDescriptor: g[e,d] = sum_k c_table[ti,tj,d,k] * f[e,k]
//   f[e,k] = (T_k(x) + 1) * 0.5 * fc,  x = 2*(r/5-1)^2 - 1,
//   fc = 0.5*cos(pi*r/5)+0.5 for r<5 else 0.
//
// Memory-bound: 176 MB HBM (48 in + 128 out) -> ~26.5 us floor at the
// 6.7 TB/s the harness fills demonstrate. Round-1 accounting puts the
// kernel at ~30 us inside a 190 us graph dominated by 2x76us poison fills.
//
// Table (16 KB) staged in LDS TRANSPOSED [j][pair]: per-edge gather banks
// = p%32 with <=2 distinct addresses per bank -> free 2-way conflict.
// This round: 2 edges/thread (float2/int2 loads, 64 B/lane stores,
// interleaved FMA chains for ILP) to shave instruction-issue overhead.

#define KMAX 8
#define NDESC 8

__device__ __forceinline__ void edge_basis(float r, float* __restrict__ f) {
    float fc = (r < 5.0f) ? (0.5f * __cosf(0.62831853071795864769f * r) + 0.5f)
                          : 0.0f;
    float u = r * 0.2f - 1.0f;
    float x = 2.0f * u * u - 1.0f;
    float h = 0.5f * fc;
    f[0] = fc;                 // (T0+1)*h = 2h = fc
    f[1] = (x + 1.0f) * h;
    float t_prev = 1.0f, t_cur = x;
    #pragma unroll
    for (int k = 2; k < KMAX; ++k) {
        float t = 2.0f * x * t_cur - t_prev;
        t_prev = t_cur; t_cur = t;
        f[k] = (t + 1.0f) * h;
    }
}

__global__ __launch_bounds__(256, 4) void radial_kernel(
    const float* __restrict__ r_ij,
    const int*   __restrict__ type_i,
    const int*   __restrict__ type_j,
    const float* __restrict__ c_table,
    float*       __restrict__ out,
    int E)
{
    // lds[j*64 + p] = c_table[p*64 + j],  j = d*8+k, p = ti*8+tj
    __shared__ float lds[64 * 64];
    const int tid = threadIdx.x;
    for (int i = tid; i < 4096; i += 256) {
        int p = i >> 6, j = i & 63;
        lds[(j << 6) | p] = c_table[i];
    }
    __syncthreads();

    const int gid    = blockIdx.x * blockDim.x + tid;
    const int stride = gridDim.x * blockDim.x;
    const int nPair  = E >> 1;

    for (int i = gid; i < nPair; i += stride) {
        float2 r2  = reinterpret_cast<const float2*>(r_ij)[i];
        int2   ti2 = reinterpret_cast<const int2*>(type_i)[i];
        int2   tj2 = reinterpret_cast<const int2*>(type_j)[i];
        int pA = (ti2.x << 3) | tj2.x;
        int pB = (ti2.y << 3) | tj2.y;

        float fA[KMAX], fB[KMAX];
        edge_basis(r2.x, fA);
        edge_basis(r2.y, fB);

        const float* colA = lds + pA;   // column pA, row stride 64 floats
        const float* colB = lds + pB;

        float accA[NDESC], accB[NDESC];
        #pragma unroll
        for (int d = 0; d < NDESC; ++d) { accA[d] = 0.0f; accB[d] = 0.0f; }

        #pragma unroll
        for (int d = 0; d < NDESC; ++d) {
            #pragma unroll
            for (int k = 0; k < KMAX; ++k) {
                int off = ((d << 3) | k) << 6;
                accA[d] = fmaf(colA[off], fA[k], accA[d]);
                accB[d] = fmaf(colB[off], fB[k], accB[d]);
            }
        }

        float4* o = reinterpret_cast<float4*>(out + (size_t)i * 16);
        o[0] = make_float4(accA[0], accA[1], accA[2], accA[3]);
        o[1] = make_float4(accA[4], accA[5], accA[6], accA[7]);
        o[2] = make_float4(accB[0], accB[1], accB[2], accB[3]);
        o[3] = make_float4(accB[4], accB[5], accB[6], accB[7]);
    }

    // tail (E odd) — E=4M is even, but stay general
    for (int e = (nPair << 1) + gid; e < E; e += stride) {
        float r = r_ij[e];
        int   p = (type_i[e] << 3) | type_j[e];
        float f[KMAX];
        edge_basis(r, f);
        const float* col = lds + p;
        float acc[NDESC];
        #pragma unroll
        for (int d = 0; d < NDESC; ++d) {
            float a = 0.0f;
            #pragma unroll
            for (int k = 0; k < KMAX; ++k)
                a = fmaf(col[((d << 3) | k) << 6], f[k], a);
            acc[d] = a;
        }
        float4* o = reinterpret_cast<float4*>(out + (size_t)e * 8);
        o[0] = make_float4(acc[0], acc[1], acc[2], acc[3]);
        o[1] = make_float4(acc[4], acc[5], acc[6], acc[7]);
    }
}

extern "C" void kernel_launch(void* const* d_in, const int* in_sizes, int n_in,
                              void* d_out, int out_size, void* d_ws, size_t ws_size,
                              hipStream_t stream) {
    const float* r_ij   = (const float*)d_in[0];
    const int*   type_i = (const int*)d_in[1];
    const int*   type_j = (const int*)d_in[2];
    const float* c_tab  = (const float*)d_in[3];
    float* out = (float*)d_out;
    int E = in_sizes[0];

    dim3 block(256);
    dim3 grid(2048);
    radial_kernel<<<grid, block, 0, stream>>>(r_ij, type_i, type_j, c_tab, out, E);
}

// Round 3
// 180.593 us; speedup vs baseline: 1.1166x; 1.1166x over previous
//
#include <hip/hip_runtime.h>

// RadialDescriptor: g[e,d] = sum_k c_table[ti,tj,d,k] * f[e,k]
//   f[e,k] = (T_k(x) + 1) * 0.5 * fc,  x = 2*(r/5-1)^2 - 1,
//   fc = 0.5*cos(pi*r/5)+0.5 for r<5 else 0.
//
// Round-2 post-mortem: kernel was LDS-pipe-bound (77us @ 1.97 TB/s HBM):
// 64x scalar ds_read_b32/edge + 1.6e7 conflict cycles ~= 153K cyc/CU = the
// whole runtime. Fix: gather via 16x ds_read_b128/edge from a row-major
// padded layout [pair][68 floats] (272B rows keep 16B alignment; row
// stagger spreads 16B spans across bank groups, group=(p%8+m)%8).
// LDS pipe time ~bytes-bound: 1.02GB / (256CU*128B/clk*2.4GHz) ~= 14us,
// below the ~23us HBM floor (FETCH 23.5MB L3-resident + WRITE 125MB).

#define KMAX 8
#define NDESC 8
#define RSTRIDE 68   // floats per table row: 272 B = 17*16 B

__device__ __forceinline__ void edge_basis(float r, float* __restrict__ f) {
    float fc = (r < 5.0f) ? (0.5f * __cosf(0.62831853071795864769f * r) + 0.5f)
                          : 0.0f;
    float u = r * 0.2f - 1.0f;
    float x = 2.0f * u * u - 1.0f;
    float h = 0.5f * fc;
    f[0] = fc;                 // (T0+1)*h = 2h = fc
    f[1] = (x + 1.0f) * h;
    float t_prev = 1.0f, t_cur = x;
    #pragma unroll
    for (int k = 2; k < KMAX; ++k) {
        float t = 2.0f * x * t_cur - t_prev;
        t_prev = t_cur; t_cur = t;
        f[k] = (t + 1.0f) * h;
    }
}

__global__ __launch_bounds__(256, 4) void radial_kernel(
    const float* __restrict__ r_ij,
    const int*   __restrict__ type_i,
    const int*   __restrict__ type_j,
    const float* __restrict__ c_table,
    float*       __restrict__ out,
    int E)
{
    // lds row p holds c_table[p][0..63] at lds[p*RSTRIDE + j]
    __shared__ float lds[64 * RSTRIDE];
    const int tid = threadIdx.x;
    // stage 1024 float4 (16 KB), 16 chunks per row
    for (int i = tid; i < 1024; i += 256) {
        float4 v = reinterpret_cast<const float4*>(c_table)[i];
        int p = i >> 4;
        int j = (i & 15) << 2;
        *reinterpret_cast<float4*>(&lds[p * RSTRIDE + j]) = v;
    }
    __syncthreads();

    const int stride = gridDim.x * blockDim.x;
    for (int e = blockIdx.x * blockDim.x + tid; e < E; e += stride) {
        float r = r_ij[e];
        int   p = (type_i[e] << 3) | type_j[e];

        float f[KMAX];
        edge_basis(r, f);

        const float4* row = reinterpret_cast<const float4*>(&lds[p * RSTRIDE]);

        float acc[NDESC];
        #pragma unroll
        for (int d = 0; d < NDESC; ++d) {
            float4 c0 = row[2 * d];       // c[p][d][0..3]
            float4 c1 = row[2 * d + 1];   // c[p][d][4..7]
            float a = fmaf(c0.x, f[0], 0.0f);
            a = fmaf(c0.y, f[1], a);
            a = fmaf(c0.z, f[2], a);
            a = fmaf(c0.w, f[3], a);
            a = fmaf(c1.x, f[4], a);
            a = fmaf(c1.y, f[5], a);
            a = fmaf(c1.z, f[6], a);
            a = fmaf(c1.w, f[7], a);
            acc[d] = a;
        }

        float4* o = reinterpret_cast<float4*>(out + (size_t)e * 8);
        o[0] = make_float4(acc[0], acc[1], acc[2], acc[3]);
        o[1] = make_float4(acc[4], acc[5], acc[6], acc[7]);
    }
}

extern "C" void kernel_launch(void* const* d_in, const int* in_sizes, int n_in,
                              void* d_out, int out_size, void* d_ws, size_t ws_size,
                              hipStream_t stream) {
    const float* r_ij   = (const float*)d_in[0];
    const int*   type_i = (const int*)d_in[1];
    const int*   type_j = (const int*)d_in[2];
    const float* c_tab  = (const float*)d_in[3];
    float* out = (float*)d_out;
    int E = in_sizes[0];

    dim3 block(256);
    dim3 grid(2048);
    radial_kernel<<<grid, block, 0, stream>>>(r_ij, type_i, type_j, c_tab, out, E);
}